// Round 14
// baseline (385.642 us; speedup 1.0000x reference)
//
#include <hip/hip_runtime.h>
#include <float.h>

#define N_NODES   50000
#define N_EDGES   800000
#define INDIM1    128
#define HC        64
#define N_GRAPHS  64
#define NEG_SLOPE 0.2f
#define CAP       64      // slot capacity/node; deg~Poisson(16); validated R5-R13
#define CSTRIDE   16      // cursor: one counter per 64B line (R12: scatter 54->49us)
#define EB        ((N_EDGES + 255) / 256)   // 3125 scatter blocks

// ---------------- CSR build (+ wedot rider block, R13-validated) ----------------
__global__ __launch_bounds__(256) void scatter_kernel(const int* __restrict__ src,
                                                      const int* __restrict__ dst,
                                                      const float* __restrict__ eattr,
                                                      int* __restrict__ cursor,
                                                      int2* __restrict__ csr_se,
                                                      const float* __restrict__ We1,
                                                      const float* __restrict__ ae1,
                                                      const float* __restrict__ We2,
                                                      const float* __restrict__ ae2,
                                                      float* __restrict__ wd) {
    int b = blockIdx.x;
    int t = threadIdx.x;
    if (b == EB) {
        if (t < 128) {
            const float* We = (t < 64) ? We1 : We2;
            const float* ae = (t < 64) ? ae1 : ae2;
            int l = t & 63;
            float p = We[l] * ae[l];
            for (int off = 1; off < 16; off <<= 1) p += __shfl_xor(p, off);
            if ((l & 15) == 0) wd[(t >> 6) * 4 + (l >> 4)] = p;
        }
        return;
    }
    int e = b * 256 + t;
    if (e < N_EDGES) {
        int d = dst[e];
        int c = atomicAdd(&cursor[(size_t)d * CSTRIDE], 1);
        if (c < CAP)
            csr_se[(size_t)d * CAP + c] = make_int2(src[e], __float_as_int(eattr[e]));
    }
}

// ---------------- node transform: 4-node register blocking ----------------
// Transform is LDS-BW bound (each Wsh b128 read fed only 4 fmas). Blocking 4
// nodes per pass amortizes each W read over 16 fmas -> LDS traffic/node /4.
// W stays LDS-staged (R5's failure was global-W + role fusion, not blocking).
template <int INDIM, int NPW>
__global__ __launch_bounds__(256) void transform_kernel(const float* __restrict__ x,
                                                        const float* __restrict__ W,
                                                        const float* __restrict__ att_s,
                                                        const float* __restrict__ att_d,
                                                        float* __restrict__ xs,
                                                        float* __restrict__ a_src,
                                                        float* __restrict__ a_dst) {
    constexpr int K4 = INDIM / 4;
    __shared__ float4 Wsh[K4 * 64];       // [k4][col]: 32KB @128, 16KB @64
    __shared__ float4 xsh[4][4][K4];      // [wave][node-in-group][k4]
    int t = threadIdx.x;
    for (int i = t; i < K4 * 64; i += 256) {
        int k4 = i >> 6, col = i & 63;
        Wsh[i] = make_float4(W[(4 * k4 + 0) * 64 + col], W[(4 * k4 + 1) * 64 + col],
                             W[(4 * k4 + 2) * 64 + col], W[(4 * k4 + 3) * 64 + col]);
    }
    __syncthreads();
    int w = t >> 6, lane = t & 63;
    float avs = att_s[lane], avd = att_d[lane];
    int node0 = blockIdx.x * (4 * NPW) + w * NPW;
    for (int ng = 0; ng < NPW; ng += 4) {
        int nbase = node0 + ng;
        if (nbase >= N_NODES) return;     // wave-uniform
        // stage 4 x-rows
        for (int q = lane; q < 4 * K4; q += 64) {
            int nn = q / K4, kk = q - nn * K4;
            int node = nbase + nn;
            xsh[w][nn][kk] = (node < N_NODES)
                ? ((const float4*)(x + (size_t)node * INDIM))[kk]
                : make_float4(0.f, 0.f, 0.f, 0.f);
        }
        float acc[4] = {0.f, 0.f, 0.f, 0.f};
#pragma unroll
        for (int k4 = 0; k4 < K4; ++k4) {
            float4 wv = Wsh[k4 * 64 + lane];          // 1 b128 read feeds 16 fmas
#pragma unroll
            for (int nn = 0; nn < 4; ++nn) {
                float4 xv = xsh[w][nn][k4];           // broadcast read
                acc[nn] = fmaf(xv.x, wv.x, acc[nn]);
                acc[nn] = fmaf(xv.y, wv.y, acc[nn]);
                acc[nn] = fmaf(xv.z, wv.z, acc[nn]);
                acc[nn] = fmaf(xv.w, wv.w, acc[nn]);
            }
        }
#pragma unroll
        for (int nn = 0; nn < 4; ++nn) {
            int node = nbase + nn;
            if (node >= N_NODES) break;
            float a = acc[nn];
            xs[(size_t)node * 64 + lane] = a;
            float ps = a * avs;
            float pd = a * avd;
            for (int off = 1; off < 16; off <<= 1) {
                ps += __shfl_xor(ps, off);
                pd += __shfl_xor(pd, off);
            }
            if ((lane & 15) == 0) {
                a_src[node * 4 + (lane >> 4)] = ps;
                a_dst[node * 4 + (lane >> 4)] = pd;
            }
        }
    }
}

// ---------------- fused attention + aggregation (R12 verbatim) ----------
__global__ __launch_bounds__(256) void aggregate_kernel(const float* __restrict__ xs,
                                                        const int2* __restrict__ csr_se,
                                                        const int* __restrict__ degp,
                                                        const float* __restrict__ a_src,
                                                        const float* __restrict__ a_dst,
                                                        const float* __restrict__ wd,
                                                        const float* __restrict__ bias,
                                                        float* __restrict__ outb,
                                                        int do_relu) {
    int w = threadIdx.x >> 6, lane = threadIdx.x & 63;
    int node = blockIdx.x * 4 + w;
    if (node >= N_NODES) return;
    int beg = node * CAP;
    int end = beg + min(degp[(size_t)node * CSTRIDE], CAP);
    const int e_idx = lane >> 2;
    const int h4 = lane & 3;
    const int h2 = lane >> 4;

    float wdv = wd[h4];
    float adv = a_dst[node * 4 + h4];

    float m = -FLT_MAX;
    float s = 0.f;
    float acc = 0.f;

    for (int j0 = beg; j0 < end; j0 += 16) {
        int j = j0 + e_idx;
        bool v = (j < end);
        int sv = 0;
        float a = -FLT_MAX;
        if (v) {
            int2 se = csr_se[j];
            sv = se.x;
            float ea = __int_as_float(se.y);
            float as = a_src[sv * 4 + h4];          // gather, 800KB L2-resident
            a = as + adv + ea * wdv;
            a = a > 0.f ? a : NEG_SLOPE * a;
        }
        float cm = a;
        cm = fmaxf(cm, __shfl_xor(cm, 4));
        cm = fmaxf(cm, __shfl_xor(cm, 8));
        cm = fmaxf(cm, __shfl_xor(cm, 16));
        cm = fmaxf(cm, __shfl_xor(cm, 32));
        float mn = fmaxf(m, cm);
        float sc = __expf(m - mn);
        float wgt = __expf(a - mn);                 // 0 for invalid slots
        s = s * sc + wgt;
        m = mn;
        acc *= __shfl(sc, h2);
#pragma unroll
        for (int e = 0; e < 16; ++e) {
            float wg = __shfl(wgt, (e << 2) | h2);
            int svb = __shfl(sv, e << 2);
            acc = fmaf(wg, xs[(size_t)svb * 64 + lane], acc);
        }
    }
    s += __shfl_xor(s, 4);
    s += __shfl_xor(s, 8);
    s += __shfl_xor(s, 16);
    s += __shfl_xor(s, 32);
    float sh = __shfl(s, h2);
    float res = (sh > 0.f) ? acc / sh : 0.f;
    res += bias[lane];
    if (do_relu) res = fmaxf(res, 0.f);
    outb[(size_t)node * 64 + lane] = res;
}

// ---------------- pooling (R12-proven: 782 blocks + atomics, then divide) ------
__global__ __launch_bounds__(256) void pool_kernel(const float* __restrict__ h,
                                                   const int* __restrict__ batch,
                                                   float* __restrict__ out) {
    int wave = (blockIdx.x * blockDim.x + threadIdx.x) >> 6;
    int lane = threadIdx.x & 63;
    int i0 = wave * 16;
    if (i0 >= N_NODES) return;
    int i1 = min(i0 + 16, N_NODES);
    float acc = 0.f;
    int gcur = batch[i0];
    for (int i = i0; i < i1; ++i) {
        int g = batch[i];
        if (g != gcur) {
            atomicAdd(&out[gcur * 64 + lane], acc);
            acc = 0.f; gcur = g;
        }
        acc += h[i * 64 + lane];
    }
    atomicAdd(&out[gcur * 64 + lane], acc);
}

__global__ void pool_div_kernel(float* __restrict__ out, const int* __restrict__ batch) {
    int g = blockIdx.x, t = threadIdx.x;
    int lo = 0, hi = N_NODES;
    while (lo < hi) { int mid = (lo + hi) >> 1; if (batch[mid] < g) lo = mid + 1; else hi = mid; }
    int lo2 = lo, hi2 = N_NODES;
    while (lo2 < hi2) { int mid = (lo2 + hi2) >> 1; if (batch[mid] <= g) lo2 = mid + 1; else hi2 = mid; }
    float c = (float)max(lo2 - lo, 1);
    out[g * 64 + t] /= c;
}

// ---------------- launch ----------------

extern "C" void kernel_launch(void* const* d_in, const int* in_sizes, int n_in,
                              void* d_out, int out_size, void* d_ws, size_t ws_size,
                              hipStream_t stream) {
    const float* x    = (const float*)d_in[0];
    const int*   eidx = (const int*)d_in[1];
    const float* eat  = (const float*)d_in[2];
    const int*   batch= (const int*)d_in[3];
    const float* W1   = (const float*)d_in[4];
    const float* We1  = (const float*)d_in[5];
    const float* as1  = (const float*)d_in[6];
    const float* ad1  = (const float*)d_in[7];
    const float* ae1  = (const float*)d_in[8];
    const float* b1   = (const float*)d_in[9];
    const float* W2   = (const float*)d_in[10];
    const float* We2  = (const float*)d_in[11];
    const float* as2  = (const float*)d_in[12];
    const float* ad2  = (const float*)d_in[13];
    const float* ae2  = (const float*)d_in[14];
    const float* b2   = (const float*)d_in[15];
    const int* src  = eidx;             // edge_index[0]
    const int* dstp = eidx + N_EDGES;   // edge_index[1]
    float* out = (float*)d_out;

    char* p = (char*)d_ws;
    auto alloc = [&](size_t bytes) {
        char* r = p;
        p += (bytes + 255) & ~(size_t)255;
        return r;
    };
    int2*  csrse  = (int2*)alloc((size_t)N_NODES * CAP * 8);       // 25.6 MB
    float* xs     = (float*)alloc((size_t)N_NODES * 64 * 4);
    float* hbuf   = (float*)alloc((size_t)N_NODES * 64 * 4);
    float* asrc   = (float*)alloc((size_t)N_NODES * 4 * 4);
    float* adst   = (float*)alloc((size_t)N_NODES * 4 * 4);
    float* wd     = (float*)alloc(64);                             // wd1[4] || wd2[4]
    int*   cursor = (int*)alloc((size_t)N_NODES * CSTRIDE * 4);    // 3.2 MB padded

    hipMemsetAsync(cursor, 0, (size_t)N_NODES * CSTRIDE * 4, stream);
    hipMemsetAsync(d_out, 0, (size_t)N_GRAPHS * 64 * 4, stream);

    const int NPW = 8;
    const int TB = (N_NODES + 4 * NPW - 1) / (4 * NPW);    // 1563
    const int NB = (N_NODES + 3) / 4;                      // 12500

    // scatter + wedot rider
    scatter_kernel<<<EB + 1, 256, 0, stream>>>(src, dstp, eat, cursor, csrse,
                                               We1, ae1, We2, ae2, wd);

    // layer 1
    transform_kernel<INDIM1, NPW><<<TB, 256, 0, stream>>>(x, W1, as1, ad1, xs, asrc, adst);
    aggregate_kernel<<<NB, 256, 0, stream>>>(xs, csrse, cursor, asrc, adst,
                                             wd, b1, hbuf, 1);
    // layer 2
    transform_kernel<HC, NPW><<<TB, 256, 0, stream>>>(hbuf, W2, as2, ad2, xs, asrc, adst);
    aggregate_kernel<<<NB, 256, 0, stream>>>(xs, csrse, cursor, asrc, adst,
                                             wd + 4, b2, hbuf, 0);
    // mean pool (R12-proven)
    int pool_waves = (N_NODES + 15) / 16;
    int pool_blocks = (pool_waves + 3) / 4;
    pool_kernel<<<pool_blocks, 256, 0, stream>>>(hbuf, batch, out);
    pool_div_kernel<<<N_GRAPHS, 64, 0, stream>>>(out, batch);
}

// Round 15
// 299.096 us; speedup vs baseline: 1.2894x; 1.2894x over previous
//
#include <hip/hip_runtime.h>
#include <float.h>

#define N_NODES   50000
#define N_EDGES   800000
#define INDIM1    128
#define HC        64
#define N_GRAPHS  64
#define NEG_SLOPE 0.2f
#define CAP       64      // slot capacity/node; deg~Poisson(16); validated R5-R14
#define CSTRIDE   16      // cursor: one counter per 64B line (R12: scatter 54->49us)
#define EB        ((N_EDGES + 255) / 256)   // 3125 scatter blocks

// ---------------- CSR build (+ wedot rider block, R13-validated) ----------------
__global__ __launch_bounds__(256) void scatter_kernel(const int* __restrict__ src,
                                                      const int* __restrict__ dst,
                                                      const float* __restrict__ eattr,
                                                      int* __restrict__ cursor,
                                                      int2* __restrict__ csr_se,
                                                      const float* __restrict__ We1,
                                                      const float* __restrict__ ae1,
                                                      const float* __restrict__ We2,
                                                      const float* __restrict__ ae2,
                                                      float* __restrict__ wd) {
    int b = blockIdx.x;
    int t = threadIdx.x;
    if (b == EB) {
        if (t < 128) {
            const float* We = (t < 64) ? We1 : We2;
            const float* ae = (t < 64) ? ae1 : ae2;
            int l = t & 63;
            float p = We[l] * ae[l];
            for (int off = 1; off < 16; off <<= 1) p += __shfl_xor(p, off);
            if ((l & 15) == 0) wd[(t >> 6) * 4 + (l >> 4)] = p;
        }
        return;
    }
    int e = b * 256 + t;
    if (e < N_EDGES) {
        int d = dst[e];
        int c = atomicAdd(&cursor[(size_t)d * CSTRIDE], 1);
        if (c < CAP)
            csr_se[(size_t)d * CAP + c] = make_int2(src[e], __float_as_int(eattr[e]));
    }
}

// ---------------- node transform: 2-node blocking, VGPR-capped ----------------
// R14 lesson: 4-node blocking + full unroll -> VGPR 256, occupancy 0.5%.
// Retry with pressure pinned: 2 nodes (W LDS-reads/node halved), unroll 4,
// __launch_bounds__(256,4) caps VGPR at 128 (4 waves/EU = 4 blocks/CU,
// matching the 36KB LDS limit).
template <int INDIM, int NPW>
__global__ __launch_bounds__(256, 4) void transform_kernel(const float* __restrict__ x,
                                                           const float* __restrict__ W,
                                                           const float* __restrict__ att_s,
                                                           const float* __restrict__ att_d,
                                                           float* __restrict__ xs,
                                                           float* __restrict__ a_src,
                                                           float* __restrict__ a_dst) {
    constexpr int K4 = INDIM / 4;
    __shared__ float4 Wsh[K4 * 64];       // [k4][col]: 32KB @128, 16KB @64
    __shared__ float4 xsh[4][2][K4];      // [wave][node-in-pair][k4]
    int t = threadIdx.x;
    for (int i = t; i < K4 * 64; i += 256) {
        int k4 = i >> 6, col = i & 63;
        Wsh[i] = make_float4(W[(4 * k4 + 0) * 64 + col], W[(4 * k4 + 1) * 64 + col],
                             W[(4 * k4 + 2) * 64 + col], W[(4 * k4 + 3) * 64 + col]);
    }
    __syncthreads();
    int w = t >> 6, lane = t & 63;
    float avs = att_s[lane], avd = att_d[lane];
    int node0 = blockIdx.x * (4 * NPW) + w * NPW;
    for (int ng = 0; ng < NPW; ng += 2) {
        int nbase = node0 + ng;
        if (nbase >= N_NODES) return;     // wave-uniform
        // stage 2 x-rows
        for (int q = lane; q < 2 * K4; q += 64) {
            int nn = q / K4, kk = q - nn * K4;
            int node = nbase + nn;
            xsh[w][nn][kk] = (node < N_NODES)
                ? ((const float4*)(x + (size_t)node * INDIM))[kk]
                : make_float4(0.f, 0.f, 0.f, 0.f);
        }
        float acc0 = 0.f, acc1 = 0.f;
#pragma unroll 4
        for (int k4 = 0; k4 < K4; ++k4) {
            float4 wv = Wsh[k4 * 64 + lane];          // 1 b128 read feeds 8 fmas
            float4 x0 = xsh[w][0][k4];
            float4 x1 = xsh[w][1][k4];
            acc0 = fmaf(x0.x, wv.x, acc0);
            acc0 = fmaf(x0.y, wv.y, acc0);
            acc0 = fmaf(x0.z, wv.z, acc0);
            acc0 = fmaf(x0.w, wv.w, acc0);
            acc1 = fmaf(x1.x, wv.x, acc1);
            acc1 = fmaf(x1.y, wv.y, acc1);
            acc1 = fmaf(x1.z, wv.z, acc1);
            acc1 = fmaf(x1.w, wv.w, acc1);
        }
#pragma unroll
        for (int nn = 0; nn < 2; ++nn) {
            int node = nbase + nn;
            if (node >= N_NODES) break;
            float a = nn ? acc1 : acc0;
            xs[(size_t)node * 64 + lane] = a;
            float ps = a * avs;
            float pd = a * avd;
            for (int off = 1; off < 16; off <<= 1) {
                ps += __shfl_xor(ps, off);
                pd += __shfl_xor(pd, off);
            }
            if ((lane & 15) == 0) {
                a_src[node * 4 + (lane >> 4)] = ps;
                a_dst[node * 4 + (lane >> 4)] = pd;
            }
        }
    }
}

// ---------------- fused attention + aggregation (R12 verbatim) ----------
__global__ __launch_bounds__(256) void aggregate_kernel(const float* __restrict__ xs,
                                                        const int2* __restrict__ csr_se,
                                                        const int* __restrict__ degp,
                                                        const float* __restrict__ a_src,
                                                        const float* __restrict__ a_dst,
                                                        const float* __restrict__ wd,
                                                        const float* __restrict__ bias,
                                                        float* __restrict__ outb,
                                                        int do_relu) {
    int w = threadIdx.x >> 6, lane = threadIdx.x & 63;
    int node = blockIdx.x * 4 + w;
    if (node >= N_NODES) return;
    int beg = node * CAP;
    int end = beg + min(degp[(size_t)node * CSTRIDE], CAP);
    const int e_idx = lane >> 2;
    const int h4 = lane & 3;
    const int h2 = lane >> 4;

    float wdv = wd[h4];
    float adv = a_dst[node * 4 + h4];

    float m = -FLT_MAX;
    float s = 0.f;
    float acc = 0.f;

    for (int j0 = beg; j0 < end; j0 += 16) {
        int j = j0 + e_idx;
        bool v = (j < end);
        int sv = 0;
        float a = -FLT_MAX;
        if (v) {
            int2 se = csr_se[j];
            sv = se.x;
            float ea = __int_as_float(se.y);
            float as = a_src[sv * 4 + h4];          // gather, 800KB L2-resident
            a = as + adv + ea * wdv;
            a = a > 0.f ? a : NEG_SLOPE * a;
        }
        float cm = a;
        cm = fmaxf(cm, __shfl_xor(cm, 4));
        cm = fmaxf(cm, __shfl_xor(cm, 8));
        cm = fmaxf(cm, __shfl_xor(cm, 16));
        cm = fmaxf(cm, __shfl_xor(cm, 32));
        float mn = fmaxf(m, cm);
        float sc = __expf(m - mn);
        float wgt = __expf(a - mn);                 // 0 for invalid slots
        s = s * sc + wgt;
        m = mn;
        acc *= __shfl(sc, h2);
#pragma unroll
        for (int e = 0; e < 16; ++e) {
            float wg = __shfl(wgt, (e << 2) | h2);
            int svb = __shfl(sv, e << 2);
            acc = fmaf(wg, xs[(size_t)svb * 64 + lane], acc);
        }
    }
    s += __shfl_xor(s, 4);
    s += __shfl_xor(s, 8);
    s += __shfl_xor(s, 16);
    s += __shfl_xor(s, 32);
    float sh = __shfl(s, h2);
    float res = (sh > 0.f) ? acc / sh : 0.f;
    res += bias[lane];
    if (do_relu) res = fmaxf(res, 0.f);
    outb[(size_t)node * 64 + lane] = res;
}

// ---------------- pooling (R12-proven) ----------------
__global__ __launch_bounds__(256) void pool_kernel(const float* __restrict__ h,
                                                   const int* __restrict__ batch,
                                                   float* __restrict__ out) {
    int wave = (blockIdx.x * blockDim.x + threadIdx.x) >> 6;
    int lane = threadIdx.x & 63;
    int i0 = wave * 16;
    if (i0 >= N_NODES) return;
    int i1 = min(i0 + 16, N_NODES);
    float acc = 0.f;
    int gcur = batch[i0];
    for (int i = i0; i < i1; ++i) {
        int g = batch[i];
        if (g != gcur) {
            atomicAdd(&out[gcur * 64 + lane], acc);
            acc = 0.f; gcur = g;
        }
        acc += h[i * 64 + lane];
    }
    atomicAdd(&out[gcur * 64 + lane], acc);
}

__global__ void pool_div_kernel(float* __restrict__ out, const int* __restrict__ batch) {
    int g = blockIdx.x, t = threadIdx.x;
    int lo = 0, hi = N_NODES;
    while (lo < hi) { int mid = (lo + hi) >> 1; if (batch[mid] < g) lo = mid + 1; else hi = mid; }
    int lo2 = lo, hi2 = N_NODES;
    while (lo2 < hi2) { int mid = (lo2 + hi2) >> 1; if (batch[mid] <= g) lo2 = mid + 1; else hi2 = mid; }
    float c = (float)max(lo2 - lo, 1);
    out[g * 64 + t] /= c;
}

// ---------------- launch ----------------

extern "C" void kernel_launch(void* const* d_in, const int* in_sizes, int n_in,
                              void* d_out, int out_size, void* d_ws, size_t ws_size,
                              hipStream_t stream) {
    const float* x    = (const float*)d_in[0];
    const int*   eidx = (const int*)d_in[1];
    const float* eat  = (const float*)d_in[2];
    const int*   batch= (const int*)d_in[3];
    const float* W1   = (const float*)d_in[4];
    const float* We1  = (const float*)d_in[5];
    const float* as1  = (const float*)d_in[6];
    const float* ad1  = (const float*)d_in[7];
    const float* ae1  = (const float*)d_in[8];
    const float* b1   = (const float*)d_in[9];
    const float* W2   = (const float*)d_in[10];
    const float* We2  = (const float*)d_in[11];
    const float* as2  = (const float*)d_in[12];
    const float* ad2  = (const float*)d_in[13];
    const float* ae2  = (const float*)d_in[14];
    const float* b2   = (const float*)d_in[15];
    const int* src  = eidx;             // edge_index[0]
    const int* dstp = eidx + N_EDGES;   // edge_index[1]
    float* out = (float*)d_out;

    char* p = (char*)d_ws;
    auto alloc = [&](size_t bytes) {
        char* r = p;
        p += (bytes + 255) & ~(size_t)255;
        return r;
    };
    int2*  csrse  = (int2*)alloc((size_t)N_NODES * CAP * 8);       // 25.6 MB
    float* xs     = (float*)alloc((size_t)N_NODES * 64 * 4);
    float* hbuf   = (float*)alloc((size_t)N_NODES * 64 * 4);
    float* asrc   = (float*)alloc((size_t)N_NODES * 4 * 4);
    float* adst   = (float*)alloc((size_t)N_NODES * 4 * 4);
    float* wd     = (float*)alloc(64);                             // wd1[4] || wd2[4]
    int*   cursor = (int*)alloc((size_t)N_NODES * CSTRIDE * 4);    // 3.2 MB padded

    hipMemsetAsync(cursor, 0, (size_t)N_NODES * CSTRIDE * 4, stream);
    hipMemsetAsync(d_out, 0, (size_t)N_GRAPHS * 64 * 4, stream);

    const int NPW = 8;
    const int TB = (N_NODES + 4 * NPW - 1) / (4 * NPW);    // 1563
    const int NB = (N_NODES + 3) / 4;                      // 12500

    // scatter + wedot rider
    scatter_kernel<<<EB + 1, 256, 0, stream>>>(src, dstp, eat, cursor, csrse,
                                               We1, ae1, We2, ae2, wd);

    // layer 1
    transform_kernel<INDIM1, NPW><<<TB, 256, 0, stream>>>(x, W1, as1, ad1, xs, asrc, adst);
    aggregate_kernel<<<NB, 256, 0, stream>>>(xs, csrse, cursor, asrc, adst,
                                             wd, b1, hbuf, 1);
    // layer 2
    transform_kernel<HC, NPW><<<TB, 256, 0, stream>>>(hbuf, W2, as2, ad2, xs, asrc, adst);
    aggregate_kernel<<<NB, 256, 0, stream>>>(xs, csrse, cursor, asrc, adst,
                                             wd + 4, b2, hbuf, 0);
    // mean pool (R12-proven)
    int pool_waves = (N_NODES + 15) / 16;
    int pool_blocks = (pool_waves + 3) / 4;
    pool_kernel<<<pool_blocks, 256, 0, stream>>>(hbuf, batch, out);
    pool_div_kernel<<<N_GRAPHS, 64, 0, stream>>>(out, batch);
}